// Round 1
// baseline (267.522 us; speedup 1.0000x reference)
//
#include <hip/hip_runtime.h>

// Problem constants (fixed by setup_inputs): B=4, S=2048, H=16, DH=64, W=4,
// Kc=512, D=1024. Output (4,2048,1024) f32.

typedef __attribute__((ext_vector_type(8))) short short8;   // 8 bf16 bit-patterns (4 VGPRs)
typedef __attribute__((ext_vector_type(4))) float f32x4;
typedef __attribute__((ext_vector_type(4))) int int4e;

#define MFMA16(A, Bf, C) __builtin_amdgcn_mfma_f32_16x16x32_bf16((A), (Bf), (C), 0, 0, 0)

static __device__ __forceinline__ unsigned short f2bf(float f) {
  unsigned int u = __builtin_bit_cast(unsigned int, f);
  u += 0x7fffu + ((u >> 16) & 1u);   // round-to-nearest-even (finite inputs only)
  return (unsigned short)(u >> 16);
}
static __device__ __forceinline__ unsigned int pack2(float a, float b) {
  return (unsigned int)f2bf(a) | ((unsigned int)f2bf(b) << 16);
}
static __device__ __forceinline__ short8 cvt8(f32x4 lo, f32x4 hi) {
  short8 r;
  r[0] = (short)f2bf(lo[0]); r[1] = (short)f2bf(lo[1]);
  r[2] = (short)f2bf(lo[2]); r[3] = (short)f2bf(lo[3]);
  r[4] = (short)f2bf(hi[0]); r[5] = (short)f2bf(hi[1]);
  r[6] = (short)f2bf(hi[2]); r[7] = (short)f2bf(hi[3]);
  return r;
}

// ---------------------------------------------------------------------------
// 1) W (1024x1024 f32, [k][n]) -> WT bf16 [n][k]  (K-contiguous for B-frags)
__global__ __launch_bounds__(256) void transpose_w_kernel(
    const float* __restrict__ W, unsigned short* __restrict__ WT) {
  const int idx = blockIdx.x * 256 + threadIdx.x;        // 1M threads
  const int k = idx >> 10, n = idx & 1023;
  WT[(size_t)n * 1024 + k] = f2bf(W[idx]);
}

// conv kernel (4,64,64) f32 flat [(w*64+i)][o] -> KT bf16 [o][w*64+i]
__global__ __launch_bounds__(256) void transpose_ck_kernel(
    const float* __restrict__ K, unsigned short* __restrict__ KT) {
  const int idx = blockIdx.x * 256 + threadIdx.x;        // 16384 threads
  const int kk = idx >> 6, o = idx & 63;
  KT[o * 256 + kk] = f2bf(K[idx]);
}

// ---------------------------------------------------------------------------
// 2) Strided conv1d compression as MFMA GEMM: M = B*H*Kc = 32768 rows, N = 64,
// K = 256 (w*64+i). One wave = 16 rows x 64 cols. tpose=0: out[row][dh]
// (for K-compressed). tpose=1: out[bh][dh][c] (V transposed for PV A-frags).
__global__ __launch_bounds__(256) void compress_kernel(
    const float* __restrict__ src, const unsigned short* __restrict__ kT,
    const float* __restrict__ bias, unsigned short* __restrict__ dst, int tpose) {
  const int tid = threadIdx.x;
  const int wid = tid >> 6, lane = tid & 63;
  const int q = lane & 15, g = lane >> 4;
  const int R0 = (blockIdx.x * 4 + wid) * 16;
  const int row = R0 + q;                 // A-frag row = lane&15
  const int bh = row >> 9, c = row & 511;
  const int b = bh >> 4, h = bh & 15;
  const float* sb = src + (((size_t)b * 2048 + (size_t)c * 4) * 16 + h) * 64;
  f32x4 acc[4];
  #pragma unroll
  for (int ct = 0; ct < 4; ++ct) acc[ct] = f32x4{0.f, 0.f, 0.f, 0.f};
  #pragma unroll
  for (int ch = 0; ch < 8; ++ch) {
    const int kk = ch * 32 + g * 8;       // contiguous 8 within one w (8 | 64)
    const int w = kk >> 6, i = kk & 63;
    const float* s8 = sb + (size_t)w * 1024 + i;
    short8 a = cvt8(*(const f32x4*)s8, *(const f32x4*)(s8 + 4));
    #pragma unroll
    for (int ct = 0; ct < 4; ++ct) {
      short8 bf = *(const short8*)(kT + (ct * 16 + q) * 256 + ch * 32 + g * 8);
      acc[ct] = MFMA16(a, bf, acc[ct]);
    }
  }
  const int ro = R0 + 4 * g;              // D row = (lane>>4)*4 + r
  #pragma unroll
  for (int ct = 0; ct < 4; ++ct) {
    const int col = ct * 16 + q;          // D col = lane&15
    const float bv = bias[col];
    #pragma unroll
    for (int r = 0; r < 4; ++r) {
      const unsigned short val = f2bf(acc[ct][r] + bv);
      const int rr = ro + r;
      if (tpose) dst[(size_t)(rr >> 9) * 32768 + (size_t)col * 512 + (rr & 511)] = val;
      else       dst[(size_t)rr * 64 + col] = val;
    }
  }
}

// ---------------------------------------------------------------------------
// 3) Attention. Block = 4 independent waves; wave owns 16 q-rows.
// Swapped QK^T: S^T[key][q] = Kc . Q^T  (per-q softmax stats lane-local).
// O accumulated transposed: O^T[dh][q] = V^T . P^T.
// Permutation semantics: output (b',h') uses Q,K from jj = h'*4+b',
// V from (b',h'), mask batch b'.
__global__ __launch_bounds__(256) void attn_kernel(
    const float* __restrict__ preq, const int* __restrict__ mask,
    const unsigned short* __restrict__ kc, const unsigned short* __restrict__ vt,
    unsigned short* __restrict__ merged) {
  __shared__ unsigned short lds[4][16 * 72];  // per-wave 16x32 P tile (stride 72 -> 16B-aligned rows)
  const int tid = threadIdx.x;
  const int wid = tid >> 6, lane = tid & 63;
  const int q = lane & 15, g = lane >> 4;
  const int bid = blockIdx.x;
  const int hp = bid & 15;                // h'  (fastest: 16 blocks share a mask tile)
  const int tile = (bid >> 4) & 31;
  const int bp = bid >> 9;                // b'
  const int jj = hp * 4 + bp;
  const int bin = jj >> 4, hin = jj & 15;
  const int s0 = tile * 64 + wid * 16;
  const int srow = s0 + q;

  // Q B-frags: B[k=dh][n=q]; lane holds col q, dh = g*8+j (and +32)
  const float* qp = preq + (((size_t)bin * 2048 + srow) * 16 + hin) * 64;
  const short8 bq0 = cvt8(*(const f32x4*)(qp + g * 8), *(const f32x4*)(qp + g * 8 + 4));
  const short8 bq1 = cvt8(*(const f32x4*)(qp + 32 + g * 8), *(const f32x4*)(qp + 32 + g * 8 + 4));

  const unsigned short* kcb = kc + (size_t)(bin * 16 + hin) * 512 * 64;
  const unsigned short* vtb = vt + (size_t)(bp * 16 + hp) * 64 * 512;
  const int* mrow = mask + ((size_t)bp * 2048 + srow) * 512;
  unsigned short* lw = lds[wid];

  f32x4 o0 = {0,0,0,0}, o1 = {0,0,0,0}, o2 = {0,0,0,0}, o3 = {0,0,0,0};
  float mrun = -INFINITY, lrun = 0.0f;

  for (int c0 = 0; c0 < 512; c0 += 32) {
    float val[8];
    #pragma unroll
    for (int sub = 0; sub < 2; ++sub) {
      const int key = c0 + sub * 16 + q;             // A row = lane&15
      const unsigned short* kr = kcb + (size_t)key * 64;
      const short8 ka0 = *(const short8*)(kr + g * 8);
      const short8 ka1 = *(const short8*)(kr + 32 + g * 8);
      f32x4 s = {0,0,0,0};
      s = MFMA16(ka0, bq0, s);
      s = MFMA16(ka1, bq1, s);
      const int4e mv = *(const int4e*)(mrow + c0 + sub * 16 + 4 * g);
      #pragma unroll
      for (int r = 0; r < 4; ++r)
        val[sub * 4 + r] = mv[r] ? s[r] * 0.125f : -1.0e9f;  // /sqrt(64), then mask
    }
    // per-q-row chunk max (keys live in regs + across the 4 lane-groups)
    float ml = val[0];
    #pragma unroll
    for (int i = 1; i < 8; ++i) ml = fmaxf(ml, val[i]);
    ml = fmaxf(ml, __shfl_xor(ml, 16));
    ml = fmaxf(ml, __shfl_xor(ml, 32));
    const float mnew = fmaxf(mrun, ml);
    const float scal = __expf(mrun - mnew);
    mrun = mnew;
    float p[8], ss = 0.f;
    #pragma unroll
    for (int i = 0; i < 8; ++i) { p[i] = __expf(val[i] - mnew); ss += p[i]; }
    ss += __shfl_xor(ss, 16);
    ss += __shfl_xor(ss, 32);
    lrun = lrun * scal + ss;
    o0 *= scal; o1 *= scal; o2 *= scal; o3 *= scal;

    // P^T -> LDS [q][c] (bf16), then read as PV B-frag (in-wave, program-ordered)
    unsigned int* U = (unsigned int*)(lw + q * 72);
    U[2 * g]     = pack2(p[0], p[1]);
    U[2 * g + 1] = pack2(p[2], p[3]);
    U[8 + 2 * g]     = pack2(p[4], p[5]);
    U[8 + 2 * g + 1] = pack2(p[6], p[7]);
    const short8 pb = *(const short8*)(lw + q * 72 + g * 8);  // B[k=c][n=q]

    const unsigned short* vr = vtb + (size_t)q * 512 + c0 + g * 8;  // A[dh][c]
    o0 = MFMA16(*(const short8*)(vr),            pb, o0);
    o1 = MFMA16(*(const short8*)(vr + 16 * 512), pb, o1);
    o2 = MFMA16(*(const short8*)(vr + 32 * 512), pb, o2);
    o3 = MFMA16(*(const short8*)(vr + 48 * 512), pb, o3);
  }

  // epilogue: normalize, transpose 64(dh) x 16(q) via LDS, coalesced bf16 store
  const float rl = 1.0f / lrun;
  {
    unsigned int* U = (unsigned int*)(lw + q * 72);
    #pragma unroll
    for (int t = 0; t < 4; ++t) {
      const f32x4 ov = (t == 0) ? o0 : (t == 1) ? o1 : (t == 2) ? o2 : o3;
      U[(t * 16 + 4 * g) >> 1]       = pack2(ov[0] * rl, ov[1] * rl);
      U[((t * 16 + 4 * g) >> 1) + 1] = pack2(ov[2] * rl, ov[3] * rl);
    }
  }
  const int i = lane >> 2, seg = lane & 3;
  const short8 w0 = *(const short8*)(lw + i * 72 + seg * 16);
  const short8 w1 = *(const short8*)(lw + i * 72 + seg * 16 + 8);
  unsigned short* mp = merged + ((size_t)(bp * 2048 + s0 + i)) * 1024 + hp * 64 + seg * 16;
  *(short8*)(mp) = w0;
  *(short8*)(mp + 8) = w1;
}

// ---------------------------------------------------------------------------
// 4) Output projection: out(8192x1024 f32) = merged(8192x1024 bf16) @ W.
// Block = 4 waves x (32 rows x 128 cols); WbT (2MB) stays L2-resident.
__global__ __launch_bounds__(256) void gemm_kernel(
    const unsigned short* __restrict__ A, const unsigned short* __restrict__ BT,
    float* __restrict__ out) {
  const int tid = threadIdx.x;
  const int wid = tid >> 6, lane = tid & 63;
  const int q = lane & 15, g = lane >> 4;
  const int bid = blockIdx.x;
  const int N0 = (bid & 7) * 128;
  const int M0 = (bid >> 3) * 128 + wid * 32;
  f32x4 acc[2][8];
  #pragma unroll
  for (int rt = 0; rt < 2; ++rt)
    #pragma unroll
    for (int ct = 0; ct < 8; ++ct) acc[rt][ct] = f32x4{0.f, 0.f, 0.f, 0.f};
  const unsigned short* a0p = A + (size_t)(M0 + q) * 1024;
  const unsigned short* a1p = A + (size_t)(M0 + 16 + q) * 1024;
  for (int k0 = 0; k0 < 1024; k0 += 32) {
    const short8 a0 = *(const short8*)(a0p + k0 + g * 8);
    const short8 a1 = *(const short8*)(a1p + k0 + g * 8);
    #pragma unroll
    for (int ct = 0; ct < 8; ++ct) {
      const short8 b = *(const short8*)(BT + (size_t)(N0 + ct * 16 + q) * 1024 + k0 + g * 8);
      acc[0][ct] = MFMA16(a0, b, acc[0][ct]);
      acc[1][ct] = MFMA16(a1, b, acc[1][ct]);
    }
  }
  #pragma unroll
  for (int rt = 0; rt < 2; ++rt)
    #pragma unroll
    for (int ct = 0; ct < 8; ++ct)
      #pragma unroll
      for (int r = 0; r < 4; ++r)
        out[(size_t)(M0 + rt * 16 + 4 * g + r) * 1024 + N0 + ct * 16 + q] = acc[rt][ct][r];
}

// ---------------------------------------------------------------------------
extern "C" void kernel_launch(void* const* d_in, const int* in_sizes, int n_in,
                              void* d_out, int out_size, void* d_ws, size_t ws_size,
                              hipStream_t stream) {
  const float* preq = (const float*)d_in[0];
  const float* prev = (const float*)d_in[1];
  const float* prek = (const float*)d_in[2];
  const float* W    = (const float*)d_in[3];
  const float* kck  = (const float*)d_in[4];
  const float* kcb  = (const float*)d_in[5];
  const float* vck  = (const float*)d_in[6];
  const float* vcb  = (const float*)d_in[7];
  const int*   msk  = (const int*)d_in[8];
  float* out = (float*)d_out;

  char* ws = (char*)d_ws;
  unsigned short* WT  = (unsigned short*)(ws);                      // 2 MB
  unsigned short* kkT = (unsigned short*)(ws + 2097152);            // 64 KB
  unsigned short* vkT = (unsigned short*)(ws + 2129920);            // 64 KB
  unsigned short* kcB = (unsigned short*)(ws + 2162688);            // 4 MB  [bh][c][dh]
  unsigned short* vcT = (unsigned short*)(ws + 6356992);            // 4 MB  [bh][dh][c]
  unsigned short* mrg = (unsigned short*)(ws + 10551296);           // 16 MB [8192][1024]

  hipLaunchKernelGGL(transpose_w_kernel,  dim3(4096), dim3(256), 0, stream, W, WT);
  hipLaunchKernelGGL(transpose_ck_kernel, dim3(64),   dim3(256), 0, stream, kck, kkT);
  hipLaunchKernelGGL(transpose_ck_kernel, dim3(64),   dim3(256), 0, stream, vck, vkT);
  hipLaunchKernelGGL(compress_kernel, dim3(512), dim3(256), 0, stream, prek, kkT, kcb, kcB, 0);
  hipLaunchKernelGGL(compress_kernel, dim3(512), dim3(256), 0, stream, prev, vkT, vcb, vcT, 1);
  hipLaunchKernelGGL(attn_kernel, dim3(2048), dim3(256), 0, stream, preq, msk, kcB, vcT, mrg);
  hipLaunchKernelGGL(gemm_kernel, dim3(512), dim3(256), 0, stream, mrg, WT, out);
}